// Round 12
// baseline (245.819 us; speedup 1.0000x reference)
//
#include <hip/hip_runtime.h>
#include <hip/hip_fp16.h>
#include <cmath>

#define NNODES 8192
#define NB 64
#define ND 5
#define MAXDEG 64
#define NBLK_T0 2048       // t0 part of t0fill: wave = one node (full 2 KB row)
#define NBLK_LAY 8192      // layers: 32768 waves = (node, batch-quarter)

// xl / xr layout: [node][b=64][hc=16] fp16 (2 KB/row). h (final, sparse): fp16 same.
// Layer wave = (node v, quarter q): lane ℓ covers (b = q*16 + (ℓ>>2), head = ℓ&3).
// XCD pinning: q = (blockIdx>>1)&3  =>  blockIdx%8 ∈ {2q,2q+1}, so quarter q's 4 MB
// xl-slice lives in XCDs {2q,2q+1} L2 (blockIdx%8 -> XCD round-robin heuristic).
// All streaming traffic (xr-in, xl'/xr' out, h, meanpart) is nontemporal so the
// reused xl-in slice stays L2-resident.

__device__ __forceinline__ float2 nt_load_f2(const void* p) {
  unsigned long long u = __builtin_nontemporal_load((const unsigned long long*)p);
  return *(float2*)&u;
}
__device__ __forceinline__ void nt_store_f2(float2 v, void* p) {
  __builtin_nontemporal_store(*(unsigned long long*)&v, (unsigned long long*)p);
}
__device__ __forceinline__ void nt_store_f(float v, void* p) {
  __builtin_nontemporal_store(*(unsigned int*)&v, (unsigned int*)p);
}

// ---------------- fused t0 + edge fill + needed mask (verified R10/R11) ----------------

__global__ void __launch_bounds__(256)
k_t0fill(const float* __restrict__ x, const float* __restrict__ Wl0, const float* __restrict__ Wr0,
         __half* __restrict__ xl0, __half* __restrict__ xr0,
         const int* __restrict__ agent, const int* __restrict__ nbr,
         int* __restrict__ cnt, int* __restrict__ slot, int* __restrict__ needed) {
  if (blockIdx.x >= NBLK_T0) {
    int eb = blockIdx.x - NBLK_T0;
    if (eb < 160) {
      int i = eb*256 + threadIdx.x;                     // 40960 edges
      int v = nbr[i];
      int pos = atomicAdd(&cnt[v], 1);                  // cnt zeroed by memset
      slot[v*MAXDEG + 1 + pos] = i/ND;                  // src node u; row 0 = self
    } else if (threadIdx.x < NB) {
      int an = agent[threadIdx.x];
      needed[an] = 1;
      #pragma unroll
      for (int d = 0; d < ND; ++d) needed[nbr[an*ND + d]] = 1;
    }
    return;
  }
  int gid = blockIdx.x*blockDim.x + threadIdx.x;
  int n = gid >> 6;
  int b = gid & 63;
  const float4* src = (const float4*)(x + (((size_t)b*NNODES + n) << 4));
  float hv[16];
  #pragma unroll
  for (int q = 0; q < 4; ++q) *(float4*)(hv+4*q) = src[q];
  float yl[16], yr[16];
  #pragma unroll
  for (int j = 0; j < 16; ++j) { yl[j] = 0.f; yr[j] = 0.f; }
  #pragma unroll
  for (int f = 0; f < 16; ++f) {
    float hf = hv[f];
    #pragma unroll
    for (int j = 0; j < 16; ++j) {
      yl[j] = fmaf(hf, Wl0[f*16+j], yl[j]);
      yr[j] = fmaf(hf, Wr0[f*16+j], yr[j]);
    }
  }
  size_t idx = ((size_t)n << 10) + (b << 4);
  __half2 lh[8], rh[8];
  #pragma unroll
  for (int j = 0; j < 8; ++j) {
    lh[j] = __floats2half2_rn(yl[2*j], yl[2*j+1]);
    rh[j] = __floats2half2_rn(yr[2*j], yr[2*j+1]);
  }
  float4* ld = (float4*)(xl0 + idx);
  ld[0] = *(float4*)&lh[0]; ld[1] = *(float4*)&lh[4];
  float4* rd = (float4*)(xr0 + idx);
  rd[0] = *(float4*)&rh[0]; rd[1] = *(float4*)&rh[4];
}

// ---------------- GATv2 layer: quarter-batch waves, XCD-pinned quarters ----------------
// sW: [0,256) WlNext, [256,512) WrNext, [512,528) att, [528,544) bias

template<bool LAST>
__global__ void __launch_bounds__(256)
k_layer(const __half* __restrict__ xlin, const __half* __restrict__ xrin,
        __half* __restrict__ xlout, __half* __restrict__ xrout,
        const float* __restrict__ WlNext, const float* __restrict__ WrNext,
        const float* __restrict__ att, const float* __restrict__ bias,
        const int* __restrict__ cnt, const int* __restrict__ slot,
        const int* __restrict__ needed, __half* __restrict__ h,
        float* __restrict__ meanpart) {
  __shared__ float sW[544];
  __shared__ float msm[4][16][17];               // LAST: mean partials (padded)
  int tid = threadIdx.x;
  int w = tid >> 6, lane = tid & 63;

  if (!LAST) {
    sW[tid]     = WlNext[tid];                   // 256 threads, 256 floats each
    sW[256+tid] = WrNext[tid];
  }
  if (tid < 16)      sW[512+tid]    = att[tid];
  else if (tid < 32) sW[512+tid]    = bias[tid-16];   // lands at 528+
  __syncthreads();

  int B = blockIdx.x;
  int q = (B >> 1) & 3;                          // quarter -> XCDs {2q,2q+1}
  int v = ((((B >> 3) << 1) | (B & 1)) << 2) + w;  // node
  int head = lane & 3;
  size_t soff = ((size_t)q << 8) + (lane << 2);  // slice offset within row

  float4 awv = *(float4*)&sW[512 + head*4];
  float aw0 = awv.x, aw1 = awv.y, aw2 = awv.z, aw3 = awv.w;

  float xr0, xr1, xr2, xr3;
  {
    float2 rx = nt_load_f2(xrin + (((size_t)v) << 10) + soff);   // 1-touch: bypass L2
    __half2* ph = (__half2*)&rx;
    float2 f0 = __half22float2(ph[0]), f1 = __half22float2(ph[1]);
    xr0 = f0.x; xr1 = f0.y; xr2 = f1.x; xr3 = f1.y;
  }

  float s = 0.f, a0 = 0.f, a1 = 0.f, a2 = 0.f, a3 = 0.f;
  int deg = cnt[v];
  int tot = deg + 1;                             // + self (row 0 = v itself)
  const int* sl = slot + v*MAXDEG;               // sl[1..deg] valid

  auto loadrow = [&](int u) -> float2 {          // cached: the reused 4 MB slice
    return *(const float2*)(xlin + (((size_t)u) << 10) + soff);
  };
  auto process = [&](float2 r) {
    __half2* ph = (__half2*)&r;
    float2 f0 = __half22float2(ph[0]), f1 = __half22float2(ph[1]);
    float t0 = f0.x, t1 = f0.y, t2 = f1.x, t3 = f1.y;
    float z0 = t0 + xr0; z0 = (z0 >= 0.f) ? z0 : 0.2f*z0;
    float z1 = t1 + xr1; z1 = (z1 >= 0.f) ? z1 : 0.2f*z1;
    float z2 = t2 + xr2; z2 = (z2 >= 0.f) ? z2 : 0.2f*z2;
    float z3 = t3 + xr3; z3 = (z3 >= 0.f) ? z3 : 0.2f*z3;
    float lg = fmaf(z0, aw0, fmaf(z1, aw1, fmaf(z2, aw2, z3*aw3)));
    float p = __expf(lg);                        // no max-rescale: logits bounded
    s += p;
    a0 = fmaf(p, t0, a0); a1 = fmaf(p, t1, a1);
    a2 = fmaf(p, t2, a2); a3 = fmaf(p, t3, a3);
  };

  // straight-line prefetch of min(tot,8) rows + prefetched depth-2 remainder
  float2 r0, r1, r2, r3, r4, r5, r6, r7, pA, pB;
  r0 = loadrow(v);
  if (tot > 1) r1 = loadrow(sl[1]);
  if (tot > 2) r2 = loadrow(sl[2]);
  if (tot > 3) r3 = loadrow(sl[3]);
  if (tot > 4) r4 = loadrow(sl[4]);
  if (tot > 5) r5 = loadrow(sl[5]);
  if (tot > 6) r6 = loadrow(sl[6]);
  if (tot > 7) r7 = loadrow(sl[7]);
  if (tot > 8) pA = loadrow(sl[8]);
  if (tot > 9) pB = loadrow(sl[9]);
  process(r0);
  if (tot > 1) process(r1);
  if (tot > 2) process(r2);
  if (tot > 3) process(r3);
  if (tot > 4) process(r4);
  if (tot > 5) process(r5);
  if (tot > 6) process(r6);
  if (tot > 7) process(r7);
  int e = 8;
  for (; e+1 < tot; e += 2) {
    float2 cA = pA; if (e+2 < tot) pA = loadrow(sl[e+2]);
    float2 cB = pB; if (e+3 < tot) pB = loadrow(sl[e+3]);
    process(cA); process(cB);
  }
  if (e < tot) process(pA);

  float inv = 1.f / s;
  float4 bsv = *(float4*)&sW[528 + head*4];
  float o0 = fmaf(a0, inv, bsv.x), o1 = fmaf(a1, inv, bsv.y);
  float o2 = fmaf(a2, inv, bsv.z), o3 = fmaf(a3, inv, bsv.w);

  if (!LAST) {
    // assemble of[16] (full o of this b) via 16 intra-wave shuffles (4 lanes/b)
    float of[16];
    int lb = lane & ~3;
    #pragma unroll
    for (int src = 0; src < 4; ++src) {
      of[src*4+0] = __shfl(o0, lb+src);
      of[src*4+1] = __shfl(o1, lb+src);
      of[src*4+2] = __shfl(o2, lb+src);
      of[src*4+3] = __shfl(o3, lb+src);
    }
    float yl0=0.f, yl1=0.f, yl2=0.f, yl3=0.f;
    float yr0=0.f, yr1=0.f, yr2=0.f, yr3=0.f;
    #pragma unroll
    for (int f = 0; f < 16; ++f) {
      float4 wl4 = *(float4*)&sW[f*16 + head*4];        // conflict-free b128 bcast
      float4 wr4 = *(float4*)&sW[256 + f*16 + head*4];
      float ofv = of[f];
      yl0 = fmaf(ofv, wl4.x, yl0); yl1 = fmaf(ofv, wl4.y, yl1);
      yl2 = fmaf(ofv, wl4.z, yl2); yl3 = fmaf(ofv, wl4.w, yl3);
      yr0 = fmaf(ofv, wr4.x, yr0); yr1 = fmaf(ofv, wr4.y, yr1);
      yr2 = fmaf(ofv, wr4.z, yr2); yr3 = fmaf(ofv, wr4.w, yr3);
    }
    float2 lo, ro;
    ((__half2*)&lo)[0] = __floats2half2_rn(yl0, yl1);
    ((__half2*)&lo)[1] = __floats2half2_rn(yl2, yl3);
    ((__half2*)&ro)[0] = __floats2half2_rn(yr0, yr1);
    ((__half2*)&ro)[1] = __floats2half2_rn(yr2, yr3);
    size_t idx = (((size_t)v) << 10) + soff;
    nt_store_f2(lo, xlout + idx);                // streaming: keep out of L2
    nt_store_f2(ro, xrout + idx);
  } else {
    if (needed[v]) {                             // sparse h: agent/neighbor rows only
      float2 ho;
      ((__half2*)&ho)[0] = __floats2half2_rn(o0, o1);
      ((__half2*)&ho)[1] = __floats2half2_rn(o2, o3);
      nt_store_f2(ho, h + (((size_t)v) << 10) + soff);
    }
    int bl = lane >> 2;
    msm[w][bl][head*4+0] = o0;
    msm[w][bl][head*4+1] = o1;
    msm[w][bl][head*4+2] = o2;
    msm[w][bl][head*4+3] = o3;
    __syncthreads();
    // block partial -> meanpart[B][bl*16+hc]  (bl within quarter)
    int bl2 = tid >> 4, hc = tid & 15;
    float ssum = msm[0][bl2][hc] + msm[1][bl2][hc] + msm[2][bl2][hc] + msm[3][bl2][hc];
    nt_store_f(ssum, meanpart + (size_t)B*256 + tid);
  }
}

// ---------------- fused tail: meanpart reduce + mean MLP + edge MLP ----------------

__global__ void __launch_bounds__(256)
k_tail(const __half* __restrict__ h, const int* __restrict__ agent,
       const int* __restrict__ nbr, const float* __restrict__ meanpart,
       const float* __restrict__ Wg1, const float* __restrict__ bg1,
       const float* __restrict__ Wg2, const float* __restrict__ bg2,
       const float* __restrict__ We1, const float* __restrict__ be1,
       const float* __restrict__ We2, const float* __restrict__ be2,
       const float* __restrict__ We3, const float* __restrict__ be3,
       float* __restrict__ out) {
  int b = blockIdx.x;
  int t = threadIdx.x;                 // 256
  __shared__ float red[256];
  __shared__ float mean[16], g1[32], aggs[64];
  __shared__ float srcv[16];
  __shared__ float tgt[5][16];
  __shared__ float e1s[15][16];
  __shared__ float e2s[15][8];
  int an = agent[b];

  // reduce this b's partials: quarter q's blocks are B = (m<<3)|(q<<1)|s
  {
    int hc = t & 15, grp = t >> 4;     // 16 groups x 64 m-values x 2 s
    int q = b >> 4, bl = b & 15;
    float s = 0.f;
    for (int m = grp*64; m < grp*64+64; ++m) {
      int B0 = (m << 3) | (q << 1);
      s += meanpart[(size_t)B0*256 + bl*16 + hc]
         + meanpart[(size_t)(B0|1)*256 + bl*16 + hc];
    }
    red[t] = s;
    __syncthreads();
    if (t < 16) {
      float m = 0.f;
      for (int g = 0; g < 16; ++g) m += red[g*16 + t];
      mean[t] = m * (1.0f/NNODES);
    }
  }
  if (t >= 64 && t < 80) srcv[t-64] = __half2float(h[((size_t)an << 10) + (b << 4) + (t-64)]);
  if (t >= 96 && t < 176) {
    int d = (t-96)/16, k = (t-96)%16;
    int nn = nbr[an*ND + d];
    tgt[d][k] = __half2float(h[((size_t)nn << 10) + (b << 4) + k]);
  }
  __syncthreads();
  if (t < 32) {
    float a = bg1[t];
    for (int f = 0; f < 16; ++f) a = fmaf(mean[f], Wg1[f*32+t], a);
    g1[t] = tanhf(a);
  }
  __syncthreads();
  if (t < 64) {
    float a = bg2[t];
    for (int f = 0; f < 32; ++f) a = fmaf(g1[f], Wg2[f*64+t], a);
    aggs[t] = tanhf(a);
  }
  __syncthreads();
  if (t < 240) {
    int j = t & 15, td = t >> 4;       // td = tk*5+d
    int tk = td/5, d = td%5;
    float a = be1[j];
    for (int k = 0; k < 16; ++k) a = fmaf(srcv[k],  We1[k*16+j],      a);
    a += We1[(16+tk)*16 + j];          // one-hot token rows 16..18
    for (int k = 0; k < 16; ++k) a = fmaf(tgt[d][k], We1[(19+k)*16+j], a);
    for (int k = 0; k < 64; ++k) a = fmaf(aggs[k],  We1[(35+k)*16+j], a);
    e1s[td][j] = tanhf(a);
  }
  __syncthreads();
  if (t < 120) {
    int j = t & 7, td = t >> 3;
    float a = be2[j];
    for (int k = 0; k < 16; ++k) a = fmaf(e1s[td][k], We2[k*8+j], a);
    e2s[td][j] = tanhf(a);
  }
  __syncthreads();
  if (t < 15) {
    float a = be3[0];
    for (int k = 0; k < 8; ++k) a = fmaf(e2s[t][k], We3[k], a);
    out[b*15 + t] = a;
  }
}

// ---------------- launch ----------------

extern "C" void kernel_launch(void* const* d_in, const int* in_sizes, int n_in,
                              void* d_out, int out_size, void* d_ws, size_t ws_size,
                              hipStream_t stream) {
  const float* x     = (const float*)d_in[0];
  const int*   agent = (const int*)  d_in[1];
  const int*   nbr   = (const int*)  d_in[2];
  const float* Wl    = (const float*)d_in[3];   // (4,16,4,4)
  const float* Wr    = (const float*)d_in[4];
  const float* att   = (const float*)d_in[5];   // (4,4,4)
  const float* bias  = (const float*)d_in[6];   // (4,16)
  const float* Wg1   = (const float*)d_in[7];
  const float* bg1   = (const float*)d_in[8];
  const float* Wg2   = (const float*)d_in[9];
  const float* bg2   = (const float*)d_in[10];
  const float* We1   = (const float*)d_in[11];
  const float* be1   = (const float*)d_in[12];
  const float* We2   = (const float*)d_in[13];
  const float* be2   = (const float*)d_in[14];
  const float* We3   = (const float*)d_in[15];
  const float* be3   = (const float*)d_in[16];
  float* out = (float*)d_out;

  char* ws = (char*)d_ws;
  size_t off = 0;
  auto alloc = [&](size_t bytes) -> void* {
    void* p = ws + off;
    off += (bytes + 255) & ~(size_t)255;
    return p;
  };
  const size_t XBYTES = (size_t)NNODES*NB*16*sizeof(__half);    // 16 MB
  __half* h    = (__half*)alloc(XBYTES);
  __half* xlA  = (__half*)alloc(XBYTES);
  __half* xlB  = (__half*)alloc(XBYTES);
  __half* xrA  = (__half*)alloc(XBYTES);
  __half* xrB  = (__half*)alloc(XBYTES);
  int*  slot   = (int*)alloc((size_t)NNODES*MAXDEG*sizeof(int));
  float* meanpart = (float*)alloc((size_t)NBLK_LAY*256*sizeof(float));  // 8 MB
  // cnt | needed: contiguous, zeroed by one memset
  int* cnt    = (int*)alloc(NNODES*sizeof(int));
  int* needed = (int*)alloc(NNODES*sizeof(int));

  hipMemsetAsync(cnt, 0, NNODES*sizeof(int)*2, stream);

  k_t0fill<<<NBLK_T0 + 161, 256, 0, stream>>>(x, Wl, Wr, xlA, xrA,
                                              agent, nbr, cnt, slot, needed);

  k_layer<false><<<NBLK_LAY, 256, 0, stream>>>(xlA, xrA, xlB, xrB, Wl + 256, Wr + 256,
                                               att,      bias,      cnt, slot, needed, nullptr, nullptr);
  k_layer<false><<<NBLK_LAY, 256, 0, stream>>>(xlB, xrB, xlA, xrA, Wl + 512, Wr + 512,
                                               att + 16, bias + 16, cnt, slot, needed, nullptr, nullptr);
  k_layer<false><<<NBLK_LAY, 256, 0, stream>>>(xlA, xrA, xlB, xrB, Wl + 768, Wr + 768,
                                               att + 32, bias + 32, cnt, slot, needed, nullptr, nullptr);
  k_layer<true ><<<NBLK_LAY, 256, 0, stream>>>(xlB, xrB, nullptr, nullptr, nullptr, nullptr,
                                               att + 48, bias + 48, cnt, slot, needed, h, meanpart);

  k_tail<<<NB, 256, 0, stream>>>(h, agent, nbr, meanpart,
                                 Wg1, bg1, Wg2, bg2,
                                 We1, be1, We2, be2, We3, be3, out);
}

// Round 13
// 236.978 us; speedup vs baseline: 1.0373x; 1.0373x over previous
//
#include <hip/hip_runtime.h>
#include <hip/hip_fp16.h>
#include <cmath>

#define NNODES 8192
#define NB 64
#define ND 5
#define MAXDEG 64
#define NBLK_T0 2048       // t0 part of t0fill: wave = one node (full 2 KB row)
#define NBLK_LAY 8192      // layers: 32768 waves = (node, batch-quarter)

// xl / xr layout: [node][b=64][hc=16] fp16 (2 KB/row). h (final, sparse): fp16 same.
// Layer wave = (node v, quarter q): lane ℓ covers (b = q*16 + (ℓ>>2), head = ℓ&3),
// reading halves [v][b][head*4..head*4+4) at offset q*256 + ℓ*4 — per-wave 512 B
// fully contiguous. One head per lane -> softmax entirely lane-local.
// R12 post-mortem: XCD pinning + nontemporal hints were neutral/negative; the
// ~3.4 TB/s scattered-granule service rate is structural. This is R11 verbatim.

// ---------------- fused t0 + edge fill + needed mask ----------------

__global__ void __launch_bounds__(256)
k_t0fill(const float* __restrict__ x, const float* __restrict__ Wl0, const float* __restrict__ Wr0,
         __half* __restrict__ xl0, __half* __restrict__ xr0,
         const int* __restrict__ agent, const int* __restrict__ nbr,
         int* __restrict__ cnt, int* __restrict__ slot, int* __restrict__ needed) {
  if (blockIdx.x >= NBLK_T0) {
    int eb = blockIdx.x - NBLK_T0;
    if (eb < 160) {
      int i = eb*256 + threadIdx.x;                     // 40960 edges
      int v = nbr[i];
      int pos = atomicAdd(&cnt[v], 1);                  // cnt zeroed by memset
      slot[v*MAXDEG + 1 + pos] = i/ND;                  // src node u; row 0 = self
    } else if (threadIdx.x < NB) {
      int an = agent[threadIdx.x];
      needed[an] = 1;
      #pragma unroll
      for (int d = 0; d < ND; ++d) needed[nbr[an*ND + d]] = 1;
    }
    return;
  }
  int gid = blockIdx.x*blockDim.x + threadIdx.x;
  int n = gid >> 6;
  int b = gid & 63;
  const float4* src = (const float4*)(x + (((size_t)b*NNODES + n) << 4));
  float hv[16];
  #pragma unroll
  for (int q = 0; q < 4; ++q) *(float4*)(hv+4*q) = src[q];
  float yl[16], yr[16];
  #pragma unroll
  for (int j = 0; j < 16; ++j) { yl[j] = 0.f; yr[j] = 0.f; }
  #pragma unroll
  for (int f = 0; f < 16; ++f) {
    float hf = hv[f];
    #pragma unroll
    for (int j = 0; j < 16; ++j) {
      yl[j] = fmaf(hf, Wl0[f*16+j], yl[j]);
      yr[j] = fmaf(hf, Wr0[f*16+j], yr[j]);
    }
  }
  size_t idx = ((size_t)n << 10) + (b << 4);
  __half2 lh[8], rh[8];
  #pragma unroll
  for (int j = 0; j < 8; ++j) {
    lh[j] = __floats2half2_rn(yl[2*j], yl[2*j+1]);
    rh[j] = __floats2half2_rn(yr[2*j], yr[2*j+1]);
  }
  float4* ld = (float4*)(xl0 + idx);
  ld[0] = *(float4*)&lh[0]; ld[1] = *(float4*)&lh[4];
  float4* rd = (float4*)(xr0 + idx);
  rd[0] = *(float4*)&rh[0]; rd[1] = *(float4*)&rh[4];
}

// ---------------- GATv2 layer: quarter-batch waves, one head per lane ----------------
// sW: [0,256) WlNext, [256,512) WrNext, [512,528) att, [528,544) bias

template<bool LAST>
__global__ void __launch_bounds__(256)
k_layer(const __half* __restrict__ xlin, const __half* __restrict__ xrin,
        __half* __restrict__ xlout, __half* __restrict__ xrout,
        const float* __restrict__ WlNext, const float* __restrict__ WrNext,
        const float* __restrict__ att, const float* __restrict__ bias,
        const int* __restrict__ cnt, const int* __restrict__ slot,
        const int* __restrict__ needed, __half* __restrict__ h,
        float* __restrict__ meanpart) {
  __shared__ float sW[544];
  __shared__ float msm[4][16][17];               // LAST: mean partials (padded)
  int tid = threadIdx.x;
  int w = tid >> 6, lane = tid & 63;

  if (!LAST) {
    sW[tid]     = WlNext[tid];                   // 256 threads, 256 floats each
    sW[256+tid] = WrNext[tid];
  }
  if (tid < 16)      sW[512+tid]    = att[tid];
  else if (tid < 32) sW[512+tid]    = bias[tid-16];   // lands at 528+
  __syncthreads();

  int wv = (blockIdx.x << 2) + w;
  int q = wv >> 13;                              // batch quarter
  int v = wv & (NNODES-1);                       // node
  int head = lane & 3;
  size_t soff = ((size_t)q << 8) + (lane << 2);  // halves offset within row

  float4 awv = *(float4*)&sW[512 + head*4];
  float aw0 = awv.x, aw1 = awv.y, aw2 = awv.z, aw3 = awv.w;

  float xr0, xr1, xr2, xr3;
  {
    float2 rx = *(const float2*)(xrin + (((size_t)v) << 10) + soff);
    __half2* ph = (__half2*)&rx;
    float2 f0 = __half22float2(ph[0]), f1 = __half22float2(ph[1]);
    xr0 = f0.x; xr1 = f0.y; xr2 = f1.x; xr3 = f1.y;
  }

  float s = 0.f, a0 = 0.f, a1 = 0.f, a2 = 0.f, a3 = 0.f;
  int deg = cnt[v];
  int tot = deg + 1;                             // + self (row 0 = v itself)
  const int* sl = slot + v*MAXDEG;               // sl[1..deg] valid

  auto loadrow = [&](int u) -> float2 {
    return *(const float2*)(xlin + (((size_t)u) << 10) + soff);
  };
  auto process = [&](float2 r) {
    __half2* ph = (__half2*)&r;
    float2 f0 = __half22float2(ph[0]), f1 = __half22float2(ph[1]);
    float t0 = f0.x, t1 = f0.y, t2 = f1.x, t3 = f1.y;
    float z0 = t0 + xr0; z0 = (z0 >= 0.f) ? z0 : 0.2f*z0;
    float z1 = t1 + xr1; z1 = (z1 >= 0.f) ? z1 : 0.2f*z1;
    float z2 = t2 + xr2; z2 = (z2 >= 0.f) ? z2 : 0.2f*z2;
    float z3 = t3 + xr3; z3 = (z3 >= 0.f) ? z3 : 0.2f*z3;
    float lg = fmaf(z0, aw0, fmaf(z1, aw1, fmaf(z2, aw2, z3*aw3)));
    float p = __expf(lg);                        // no max-rescale: logits bounded
    s += p;
    a0 = fmaf(p, t0, a0); a1 = fmaf(p, t1, a1);
    a2 = fmaf(p, t2, a2); a3 = fmaf(p, t3, a3);
  };

  // straight-line prefetch of min(tot,8) rows + prefetched depth-2 remainder
  float2 r0, r1, r2, r3, r4, r5, r6, r7, pA, pB;
  r0 = loadrow(v);
  if (tot > 1) r1 = loadrow(sl[1]);
  if (tot > 2) r2 = loadrow(sl[2]);
  if (tot > 3) r3 = loadrow(sl[3]);
  if (tot > 4) r4 = loadrow(sl[4]);
  if (tot > 5) r5 = loadrow(sl[5]);
  if (tot > 6) r6 = loadrow(sl[6]);
  if (tot > 7) r7 = loadrow(sl[7]);
  if (tot > 8) pA = loadrow(sl[8]);
  if (tot > 9) pB = loadrow(sl[9]);
  process(r0);
  if (tot > 1) process(r1);
  if (tot > 2) process(r2);
  if (tot > 3) process(r3);
  if (tot > 4) process(r4);
  if (tot > 5) process(r5);
  if (tot > 6) process(r6);
  if (tot > 7) process(r7);
  int e = 8;
  for (; e+1 < tot; e += 2) {
    float2 cA = pA; if (e+2 < tot) pA = loadrow(sl[e+2]);
    float2 cB = pB; if (e+3 < tot) pB = loadrow(sl[e+3]);
    process(cA); process(cB);
  }
  if (e < tot) process(pA);

  float inv = 1.f / s;
  float4 bsv = *(float4*)&sW[528 + head*4];
  float o0 = fmaf(a0, inv, bsv.x), o1 = fmaf(a1, inv, bsv.y);
  float o2 = fmaf(a2, inv, bsv.z), o3 = fmaf(a3, inv, bsv.w);

  if (!LAST) {
    // assemble of[16] (full o of this b) via 16 intra-wave shuffles (4 lanes/b)
    float of[16];
    int lb = lane & ~3;
    #pragma unroll
    for (int src = 0; src < 4; ++src) {
      of[src*4+0] = __shfl(o0, lb+src);
      of[src*4+1] = __shfl(o1, lb+src);
      of[src*4+2] = __shfl(o2, lb+src);
      of[src*4+3] = __shfl(o3, lb+src);
    }
    float yl0=0.f, yl1=0.f, yl2=0.f, yl3=0.f;
    float yr0=0.f, yr1=0.f, yr2=0.f, yr3=0.f;
    #pragma unroll
    for (int f = 0; f < 16; ++f) {
      float4 wl4 = *(float4*)&sW[f*16 + head*4];        // conflict-free b128 bcast
      float4 wr4 = *(float4*)&sW[256 + f*16 + head*4];
      float ofv = of[f];
      yl0 = fmaf(ofv, wl4.x, yl0); yl1 = fmaf(ofv, wl4.y, yl1);
      yl2 = fmaf(ofv, wl4.z, yl2); yl3 = fmaf(ofv, wl4.w, yl3);
      yr0 = fmaf(ofv, wr4.x, yr0); yr1 = fmaf(ofv, wr4.y, yr1);
      yr2 = fmaf(ofv, wr4.z, yr2); yr3 = fmaf(ofv, wr4.w, yr3);
    }
    float2 lo, ro;
    ((__half2*)&lo)[0] = __floats2half2_rn(yl0, yl1);
    ((__half2*)&lo)[1] = __floats2half2_rn(yl2, yl3);
    ((__half2*)&ro)[0] = __floats2half2_rn(yr0, yr1);
    ((__half2*)&ro)[1] = __floats2half2_rn(yr2, yr3);
    size_t idx = (((size_t)v) << 10) + soff;
    *(float2*)(xlout + idx) = lo;
    *(float2*)(xrout + idx) = ro;
  } else {
    if (needed[v]) {                             // sparse h: agent/neighbor rows only
      float2 ho;
      ((__half2*)&ho)[0] = __floats2half2_rn(o0, o1);
      ((__half2*)&ho)[1] = __floats2half2_rn(o2, o3);
      *(float2*)(h + (((size_t)v) << 10) + soff) = ho;
    }
    int bl = lane >> 2;
    msm[w][bl][head*4+0] = o0;
    msm[w][bl][head*4+1] = o1;
    msm[w][bl][head*4+2] = o2;
    msm[w][bl][head*4+3] = o3;
    __syncthreads();
    // block partial: sum 4 waves -> meanpart[blk][bl*16+hc]  (bl within quarter)
    int bl2 = tid >> 4, hc = tid & 15;
    float ssum = msm[0][bl2][hc] + msm[1][bl2][hc] + msm[2][bl2][hc] + msm[3][bl2][hc];
    meanpart[(size_t)blockIdx.x*256 + tid] = ssum;
  }
}

// ---------------- fused tail: meanpart reduce + mean MLP + edge MLP ----------------

__global__ void __launch_bounds__(256)
k_tail(const __half* __restrict__ h, const int* __restrict__ agent,
       const int* __restrict__ nbr, const float* __restrict__ meanpart,
       const float* __restrict__ Wg1, const float* __restrict__ bg1,
       const float* __restrict__ Wg2, const float* __restrict__ bg2,
       const float* __restrict__ We1, const float* __restrict__ be1,
       const float* __restrict__ We2, const float* __restrict__ be2,
       const float* __restrict__ We3, const float* __restrict__ be3,
       float* __restrict__ out) {
  int b = blockIdx.x;
  int t = threadIdx.x;                 // 256
  __shared__ float red[256];
  __shared__ float mean[16], g1[32], aggs[64];
  __shared__ float srcv[16];
  __shared__ float tgt[5][16];
  __shared__ float e1s[15][16];
  __shared__ float e2s[15][8];
  int an = agent[b];

  // reduce this b's partials: its quarter q=b>>4 owns blocks [q*2048,(q+1)*2048)
  {
    int hc = t & 15, grp = t >> 4;     // 16 groups x 128 blocks
    int q = b >> 4, bl = b & 15;
    float s = 0.f;
    int base = q*2048 + grp*128;
    for (int p = 0; p < 128; ++p)
      s += meanpart[(size_t)(base+p)*256 + bl*16 + hc];
    red[t] = s;
    __syncthreads();
    if (t < 16) {
      float m = 0.f;
      for (int g = 0; g < 16; ++g) m += red[g*16 + t];
      mean[t] = m * (1.0f/NNODES);
    }
  }
  if (t >= 64 && t < 80) srcv[t-64] = __half2float(h[((size_t)an << 10) + (b << 4) + (t-64)]);
  if (t >= 96 && t < 176) {
    int d = (t-96)/16, k = (t-96)%16;
    int nn = nbr[an*ND + d];
    tgt[d][k] = __half2float(h[((size_t)nn << 10) + (b << 4) + k]);
  }
  __syncthreads();
  if (t < 32) {
    float a = bg1[t];
    for (int f = 0; f < 16; ++f) a = fmaf(mean[f], Wg1[f*32+t], a);
    g1[t] = tanhf(a);
  }
  __syncthreads();
  if (t < 64) {
    float a = bg2[t];
    for (int f = 0; f < 32; ++f) a = fmaf(g1[f], Wg2[f*64+t], a);
    aggs[t] = tanhf(a);
  }
  __syncthreads();
  if (t < 240) {
    int j = t & 15, td = t >> 4;       // td = tk*5+d
    int tk = td/5, d = td%5;
    float a = be1[j];
    for (int k = 0; k < 16; ++k) a = fmaf(srcv[k],  We1[k*16+j],      a);
    a += We1[(16+tk)*16 + j];          // one-hot token rows 16..18
    for (int k = 0; k < 16; ++k) a = fmaf(tgt[d][k], We1[(19+k)*16+j], a);
    for (int k = 0; k < 64; ++k) a = fmaf(aggs[k],  We1[(35+k)*16+j], a);
    e1s[td][j] = tanhf(a);
  }
  __syncthreads();
  if (t < 120) {
    int j = t & 7, td = t >> 3;
    float a = be2[j];
    for (int k = 0; k < 16; ++k) a = fmaf(e1s[td][k], We2[k*8+j], a);
    e2s[td][j] = tanhf(a);
  }
  __syncthreads();
  if (t < 15) {
    float a = be3[0];
    for (int k = 0; k < 8; ++k) a = fmaf(e2s[t][k], We3[k], a);
    out[b*15 + t] = a;
  }
}

// ---------------- launch ----------------

extern "C" void kernel_launch(void* const* d_in, const int* in_sizes, int n_in,
                              void* d_out, int out_size, void* d_ws, size_t ws_size,
                              hipStream_t stream) {
  const float* x     = (const float*)d_in[0];
  const int*   agent = (const int*)  d_in[1];
  const int*   nbr   = (const int*)  d_in[2];
  const float* Wl    = (const float*)d_in[3];   // (4,16,4,4)
  const float* Wr    = (const float*)d_in[4];
  const float* att   = (const float*)d_in[5];   // (4,4,4)
  const float* bias  = (const float*)d_in[6];   // (4,16)
  const float* Wg1   = (const float*)d_in[7];
  const float* bg1   = (const float*)d_in[8];
  const float* Wg2   = (const float*)d_in[9];
  const float* bg2   = (const float*)d_in[10];
  const float* We1   = (const float*)d_in[11];
  const float* be1   = (const float*)d_in[12];
  const float* We2   = (const float*)d_in[13];
  const float* be2   = (const float*)d_in[14];
  const float* We3   = (const float*)d_in[15];
  const float* be3   = (const float*)d_in[16];
  float* out = (float*)d_out;

  char* ws = (char*)d_ws;
  size_t off = 0;
  auto alloc = [&](size_t bytes) -> void* {
    void* p = ws + off;
    off += (bytes + 255) & ~(size_t)255;
    return p;
  };
  const size_t XBYTES = (size_t)NNODES*NB*16*sizeof(__half);    // 16 MB
  __half* h    = (__half*)alloc(XBYTES);
  __half* xlA  = (__half*)alloc(XBYTES);
  __half* xlB  = (__half*)alloc(XBYTES);
  __half* xrA  = (__half*)alloc(XBYTES);
  __half* xrB  = (__half*)alloc(XBYTES);
  int*  slot   = (int*)alloc((size_t)NNODES*MAXDEG*sizeof(int));
  float* meanpart = (float*)alloc((size_t)NBLK_LAY*256*sizeof(float));  // 8 MB
  // cnt | needed: contiguous, zeroed by one memset
  int* cnt    = (int*)alloc(NNODES*sizeof(int));
  int* needed = (int*)alloc(NNODES*sizeof(int));

  hipMemsetAsync(cnt, 0, NNODES*sizeof(int)*2, stream);

  k_t0fill<<<NBLK_T0 + 161, 256, 0, stream>>>(x, Wl, Wr, xlA, xrA,
                                              agent, nbr, cnt, slot, needed);

  k_layer<false><<<NBLK_LAY, 256, 0, stream>>>(xlA, xrA, xlB, xrB, Wl + 256, Wr + 256,
                                               att,      bias,      cnt, slot, needed, nullptr, nullptr);
  k_layer<false><<<NBLK_LAY, 256, 0, stream>>>(xlB, xrB, xlA, xrA, Wl + 512, Wr + 512,
                                               att + 16, bias + 16, cnt, slot, needed, nullptr, nullptr);
  k_layer<false><<<NBLK_LAY, 256, 0, stream>>>(xlA, xrA, xlB, xrB, Wl + 768, Wr + 768,
                                               att + 32, bias + 32, cnt, slot, needed, nullptr, nullptr);
  k_layer<true ><<<NBLK_LAY, 256, 0, stream>>>(xlB, xrB, nullptr, nullptr, nullptr, nullptr,
                                               att + 48, bias + 48, cnt, slot, needed, h, meanpart);

  k_tail<<<NB, 256, 0, stream>>>(h, agent, nbr, meanpart,
                                 Wg1, bg1, Wg2, bg2,
                                 We1, be1, We2, be2, We3, be3, out);
}